// Round 1
// baseline (799.294 us; speedup 1.0000x reference)
//
#include <hip/hip_runtime.h>

#define TT    8192
#define DI    4096
#define DOUT  4096
#define LLORA 8
#define RLORA 16

typedef __bf16 bf16;
typedef __attribute__((ext_vector_type(8))) __bf16 bf16x8;
typedef __attribute__((ext_vector_type(4))) __bf16 bf16x4;
typedef __attribute__((ext_vector_type(4))) float  f32x4;

// ---- d_ws layout (bytes) ----
// xb  : x as bf16, row-major [TT][DI]            64 MiB
// wkb : W_base as bf16, row-major [DOUT][DI]     32 MiB
// wab : WA flat as bf16, [L*R][DI]                1 MiB
// u   : u_scaled f32 [TT][RLORA]                 0.5 MiB
static const size_t XB_OFF  = 0;
static const size_t WKB_OFF = (size_t)TT * DI * 2;
static const size_t WAB_OFF = WKB_OFF + (size_t)DOUT * DI * 2;
static const size_t U_OFF   = WAB_OFF + (size_t)LLORA * RLORA * DI * 2;

// async global->LDS, 16B per lane. LDS dest must be linear (wave-uniform base
// + lane*16); any swizzle is applied on the GLOBAL source address (m173).
__device__ __forceinline__ void gload_lds16(const bf16* g, bf16* l) {
    __builtin_amdgcn_global_load_lds(
        (const __attribute__((address_space(1))) void*)g,
        (__attribute__((address_space(3))) void*)l,
        16, 0, 0);
}

// ---------------- P1: convert W_base and WA to bf16 ----------------
__global__ __launch_bounds__(256) void convert_w(
    const float* __restrict__ W, const float* __restrict__ WA,
    bf16* __restrict__ wkb, bf16* __restrict__ wab)
{
    const int NW4 = (DOUT * DI) / 4;          // 4194304
    const int NA4 = (LLORA * RLORA * DI) / 4; // 131072
    int idx = blockIdx.x * 256 + threadIdx.x;
    int stride = gridDim.x * 256;
    for (int i = idx; i < NW4 + NA4; i += stride) {
        f32x4 v;
        if (i < NW4) v = ((const f32x4*)W)[i];
        else         v = ((const f32x4*)WA)[i - NW4];
        bf16x4 h;
        h[0] = (bf16)v[0]; h[1] = (bf16)v[1]; h[2] = (bf16)v[2]; h[3] = (bf16)v[3];
        if (i < NW4) ((bf16x4*)wkb)[i] = h;
        else         ((bf16x4*)wab)[i - NW4] = h;
    }
}

// ---------------- P2: convert x -> bf16 AND compute u_scaled ----------------
// grid = 64 token-tiles * 4 K-splits. Each block: M=128 tokens, N=128 (l*16+r),
// K=1024. MFMA vs WA_bf16; epilogue atomicAdd of scaling*u into u[].
__global__ __launch_bounds__(256) void prep_x_u(
    const float* __restrict__ x, const bf16* __restrict__ wab,
    const float* __restrict__ scaling, const int* __restrict__ tl,
    bf16* __restrict__ xb, float* __restrict__ u)
{
    __shared__ bf16 sA[128 * 64];
    __shared__ bf16 sB[128 * 64];
    const int bid = blockIdx.x;
    const int bm = bid >> 2, kb = bid & 3;
    const int t0 = bm * 128;
    const int tid  = threadIdx.x;
    const int lane = tid & 63;
    const int wv = tid >> 6;
    const int wr = wv >> 1, wc = wv & 1;

    f32x4 acc[4][4] = {};

    for (int kt = 0; kt < 16; ++kt) {
        const int k = kb * 1024 + kt * 64;
        // stage x: f32 load -> bf16 -> global xb + swizzled LDS write
#pragma unroll
        for (int j = 0; j < 8; ++j) {
            int c = j * 256 + tid;          // 0..2047
            int row = c >> 4, cf4 = c & 15; // 16 float4 per 64-elem row
            f32x4 v = *(const f32x4*)(x + (size_t)(t0 + row) * DI + k + cf4 * 4);
            bf16x4 h;
            h[0] = (bf16)v[0]; h[1] = (bf16)v[1]; h[2] = (bf16)v[2]; h[3] = (bf16)v[3];
            *(bf16x4*)(xb + (size_t)(t0 + row) * DI + k + cf4 * 4) = h;
            int byte = row * 128 + ((cf4 * 8) ^ ((row & 7) << 4));
            *(bf16x4*)((char*)sA + byte) = h;
        }
        // stage WA tile via global_load_lds (source pre-swizzled)
#pragma unroll
        for (int j = 0; j < 4; ++j) {
            int ci = j * 256 + tid;         // 0..1023
            int row = ci >> 3;
            int sl = (ci & 7) ^ (row & 7);
            gload_lds16(wab + (size_t)row * DI + k + sl * 8, sB + ci * 8);
        }
        __syncthreads();
#pragma unroll
        for (int ks = 0; ks < 2; ++ks) {
            bf16x8 af[4], bg[4];
#pragma unroll
            for (int mi = 0; mi < 4; ++mi) {
                int row = wr * 64 + mi * 16 + (lane & 15);
                int byte = row * 128 + (((ks * 64) + (lane >> 4) * 16) ^ ((row & 7) << 4));
                af[mi] = *(const bf16x8*)((const char*)sA + byte);
            }
#pragma unroll
            for (int ni = 0; ni < 4; ++ni) {
                int row = wc * 64 + ni * 16 + (lane & 15);
                int byte = row * 128 + (((ks * 64) + (lane >> 4) * 16) ^ ((row & 7) << 4));
                bg[ni] = *(const bf16x8*)((const char*)sB + byte);
            }
#pragma unroll
            for (int mi = 0; mi < 4; ++mi)
#pragma unroll
                for (int ni = 0; ni < 4; ++ni)
                    acc[mi][ni] = __builtin_amdgcn_mfma_f32_16x16x32_bf16(
                        af[mi], bg[ni], acc[mi][ni], 0, 0, 0);
        }
        __syncthreads();
    }

    // epilogue: select adapter rows, scale, atomic-accumulate K-splits
    const int qw = lane >> 4, cl = lane & 15;
#pragma unroll
    for (int mi = 0; mi < 4; ++mi) {
#pragma unroll
        for (int rr = 0; rr < 4; ++rr) {
            int t = t0 + wr * 64 + mi * 16 + qw * 4 + rr;
            int lt = tl[t];
            float s = scaling[lt];
#pragma unroll
            for (int ni = 0; ni < 4; ++ni) {
                int lr = wc * 64 + ni * 16 + cl;
                if ((lr >> 4) == lt)
                    atomicAdd(&u[t * RLORA + (lr & 15)], s * acc[mi][ni][rr]);
            }
        }
    }
}

// ---------------- Main: 128x128 bf16 GEMM + fused bias/LoRA epilogue ----------
__global__ __launch_bounds__(256) void gemm_main(
    const bf16* __restrict__ xb, const bf16* __restrict__ wkb,
    const float* __restrict__ bb, const float* __restrict__ WBw,
    const float* __restrict__ u, const int* __restrict__ tl,
    float* __restrict__ out)
{
    __shared__ bf16 smem[32768]; // A0 A1 | B0 B1, each 128x64 bf16 (16KiB)
    const int bid = blockIdx.x;
    const int wg = (bid & 7) * 256 + (bid >> 3); // XCD-bijective swizzle (2048 % 8 == 0)
    const int bm = wg >> 5, bn = wg & 31;
    const int brow = bm * 128, bcol = bn * 128;
    const int tid  = threadIdx.x;
    const int lane = tid & 63;
    const int wv = tid >> 6;
    const int wr = wv >> 1, wc = wv & 1;

    f32x4 acc[4][4] = {};

    // per-thread staging sources (pre-swizzled global column slot)
    const bf16* asrc[4];
    const bf16* bsrc[4];
#pragma unroll
    for (int j = 0; j < 4; ++j) {
        int ci = j * 256 + tid;
        int row = ci >> 3;
        int sl = (ci & 7) ^ (row & 7);
        asrc[j] = xb  + (size_t)(brow + row) * DI + sl * 8;
        bsrc[j] = wkb + (size_t)(bcol + row) * DI + sl * 8;
    }

    auto stage = [&](int d, int kt) {
        bf16* sa = smem + d * 8192;
        bf16* sb = smem + 16384 + d * 8192;
#pragma unroll
        for (int j = 0; j < 4; ++j)
            gload_lds16(asrc[j] + kt * 64, sa + (j * 256 + tid) * 8);
#pragma unroll
        for (int j = 0; j < 4; ++j)
            gload_lds16(bsrc[j] + kt * 64, sb + (j * 256 + tid) * 8);
    };

    auto compute = [&](int d) {
        const char* sa = (const char*)(smem + d * 8192);
        const char* sb = (const char*)(smem + 16384 + d * 8192);
#pragma unroll
        for (int ks = 0; ks < 2; ++ks) {
            bf16x8 af[4], bg[4];
#pragma unroll
            for (int mi = 0; mi < 4; ++mi) {
                int row = wr * 64 + mi * 16 + (lane & 15);
                int byte = row * 128 + (((ks * 64) + (lane >> 4) * 16) ^ ((row & 7) << 4));
                af[mi] = *(const bf16x8*)(sa + byte);
            }
#pragma unroll
            for (int ni = 0; ni < 4; ++ni) {
                int row = wc * 64 + ni * 16 + (lane & 15);
                int byte = row * 128 + (((ks * 64) + (lane >> 4) * 16) ^ ((row & 7) << 4));
                bg[ni] = *(const bf16x8*)(sb + byte);
            }
#pragma unroll
            for (int mi = 0; mi < 4; ++mi)
#pragma unroll
                for (int ni = 0; ni < 4; ++ni)
                    acc[mi][ni] = __builtin_amdgcn_mfma_f32_16x16x32_bf16(
                        af[mi], bg[ni], acc[mi][ni], 0, 0, 0);
        }
    };

    stage(0, 0);
    __syncthreads();
    for (int kt = 0; kt < 64; kt += 2) {
        stage(1, kt + 1);            // prefetch next while computing cur
        compute(0);
        __syncthreads();             // drains vmcnt(0): buf1 staged, buf0 reads done
        if (kt + 2 < 64) stage(0, kt + 2);
        compute(1);
        __syncthreads();
    }

    // ---- epilogue: out = acc + b + dot16(u_scaled[t], WB[l_t][o]) ----
    float* uld = (float*)smem;            // [128][16] f32 (8 KiB)
    int*   tld = (int*)(smem + 4096);     // byte offset 8192, 128 ints
    {
        const f32x4* ug = (const f32x4*)(u + (size_t)brow * RLORA);
        f32x4* us = (f32x4*)uld;
        us[tid]       = ug[tid];
        us[256 + tid] = ug[256 + tid];
        if (tid < 128) tld[tid] = tl[brow + tid];
    }
    __syncthreads();
    const int luni = (tld[0] == tld[127]) ? tld[0] : -1; // sorted => uniform iff endpoints equal
    const int qw = lane >> 4, cl = lane & 15;

    int   ocol[4];
    float bv[4];
#pragma unroll
    for (int ni = 0; ni < 4; ++ni) {
        ocol[ni] = bcol + wc * 64 + ni * 16 + cl;
        bv[ni] = bb[ocol[ni]];
    }
    f32x4 wbv[4][4];
    if (luni >= 0) {
#pragma unroll
        for (int ni = 0; ni < 4; ++ni) {
            const f32x4* wp = (const f32x4*)(WBw + ((size_t)luni * DOUT + ocol[ni]) * RLORA);
#pragma unroll
            for (int j = 0; j < 4; ++j) wbv[ni][j] = wp[j];
        }
    }

#pragma unroll
    for (int mi = 0; mi < 4; ++mi) {
#pragma unroll
        for (int rr = 0; rr < 4; ++rr) {
            int t_loc = wr * 64 + mi * 16 + qw * 4 + rr;
            const float* uv = uld + t_loc * 16;
            int lt = (luni >= 0) ? luni : tld[t_loc];
            float* op = out + (size_t)(brow + t_loc) * DOUT;
#pragma unroll
            for (int ni = 0; ni < 4; ++ni) {
                f32x4 w0, w1, w2, w3;
                if (luni >= 0) {
                    w0 = wbv[ni][0]; w1 = wbv[ni][1]; w2 = wbv[ni][2]; w3 = wbv[ni][3];
                } else {
                    const f32x4* wp = (const f32x4*)(WBw + ((size_t)lt * DOUT + ocol[ni]) * RLORA);
                    w0 = wp[0]; w1 = wp[1]; w2 = wp[2]; w3 = wp[3];
                }
                float dot = 0.f;
#pragma unroll
                for (int r = 0; r < 4; ++r)
                    dot += uv[r] * w0[r] + uv[4 + r] * w1[r]
                         + uv[8 + r] * w2[r] + uv[12 + r] * w3[r];
                op[ocol[ni]] = acc[mi][ni][rr] + bv[ni] + dot;
            }
        }
    }
}

extern "C" void kernel_launch(void* const* d_in, const int* in_sizes, int n_in,
                              void* d_out, int out_size, void* d_ws, size_t ws_size,
                              hipStream_t stream) {
    const float* x   = (const float*)d_in[0];
    const float* W   = (const float*)d_in[1];
    const float* bb  = (const float*)d_in[2];
    const float* WA  = (const float*)d_in[3];
    const float* WBw = (const float*)d_in[4];
    const float* sc  = (const float*)d_in[5];
    const int*   tl  = (const int*)d_in[6];
    float* out = (float*)d_out;

    char* ws = (char*)d_ws;
    bf16*  xb  = (bf16*)(ws + XB_OFF);
    bf16*  wkb = (bf16*)(ws + WKB_OFF);
    bf16*  wab = (bf16*)(ws + WAB_OFF);
    float* u   = (float*)(ws + U_OFF);

    hipMemsetAsync(u, 0, (size_t)TT * RLORA * sizeof(float), stream);
    convert_w<<<2048, 256, 0, stream>>>(W, WA, wkb, wab);
    prep_x_u<<<256, 256, 0, stream>>>(x, wab, sc, tl, xb, u);
    gemm_main<<<2048, 256, 0, stream>>>(xb, wkb, bb, WBw, u, tl, out);
}

// Round 2
// 722.440 us; speedup vs baseline: 1.1064x; 1.1064x over previous
//
#include <hip/hip_runtime.h>

#define TT    8192
#define DI    4096
#define DOUT  4096
#define LLORA 8
#define RLORA 16
#define NKT   64     // K tiles of 64 in gemm_main

typedef __bf16 bf16;
typedef __attribute__((ext_vector_type(8))) __bf16 bf16x8;
typedef __attribute__((ext_vector_type(4))) __bf16 bf16x4;
typedef __attribute__((ext_vector_type(4))) float  f32x4;

// ---- d_ws layout (bytes) ----
static const size_t XB_OFF  = 0;                                  // x bf16 [TT][DI]      64 MiB
static const size_t WKB_OFF = (size_t)TT * DI * 2;                // W bf16 [DOUT][DI]    32 MiB
static const size_t WAB_OFF = WKB_OFF + (size_t)DOUT * DI * 2;    // WA bf16 [L*R][DI]     1 MiB
static const size_t U_OFF   = WAB_OFF + (size_t)LLORA * RLORA * DI * 2; // u f32 [TT][R]  0.5 MiB

__device__ __forceinline__ void gload_lds16(const bf16* g, bf16* l) {
    __builtin_amdgcn_global_load_lds(
        (const __attribute__((address_space(1))) void*)g,
        (__attribute__((address_space(3))) void*)l,
        16, 0, 0);
}

// ---------------- P1: convert W_base and WA to bf16 ----------------
__global__ __launch_bounds__(256) void convert_w(
    const float* __restrict__ W, const float* __restrict__ WA,
    bf16* __restrict__ wkb, bf16* __restrict__ wab)
{
    const int NW4 = (DOUT * DI) / 4;
    const int NA4 = (LLORA * RLORA * DI) / 4;
    int idx = blockIdx.x * 256 + threadIdx.x;
    int stride = gridDim.x * 256;
    for (int i = idx; i < NW4 + NA4; i += stride) {
        f32x4 v;
        if (i < NW4) v = ((const f32x4*)W)[i];
        else         v = ((const f32x4*)WA)[i - NW4];
        bf16x4 h;
        h[0] = (bf16)v[0]; h[1] = (bf16)v[1]; h[2] = (bf16)v[2]; h[3] = (bf16)v[3];
        if (i < NW4) ((bf16x4*)wkb)[i] = h;
        else         ((bf16x4*)wab)[i - NW4] = h;
    }
}

// ---------------- P2: convert x -> bf16 AND compute u_scaled ----------------
// grid = 64 token-tiles * 8 K-splits (512 blocks, 2/CU). M=128 tokens,
// N=128 (l*16+r), K=512 per block.
__global__ __launch_bounds__(256) void prep_x_u(
    const float* __restrict__ x, const bf16* __restrict__ wab,
    const float* __restrict__ scaling, const int* __restrict__ tl,
    bf16* __restrict__ xb, float* __restrict__ u)
{
    __shared__ bf16 sA[128 * 64];
    __shared__ bf16 sB[128 * 64];
    const int bid = blockIdx.x;
    const int bm = bid >> 3, kb = bid & 7;
    const int t0 = bm * 128;
    const int tid  = threadIdx.x;
    const int lane = tid & 63;
    const int wv = tid >> 6;
    const int wr = wv >> 1, wc = wv & 1;

    f32x4 acc[4][4] = {};

    for (int kt = 0; kt < 8; ++kt) {
        const int k = kb * 512 + kt * 64;
#pragma unroll
        for (int j = 0; j < 8; ++j) {
            int c = j * 256 + tid;
            int row = c >> 4, cf4 = c & 15;
            f32x4 v = *(const f32x4*)(x + (size_t)(t0 + row) * DI + k + cf4 * 4);
            bf16x4 h;
            h[0] = (bf16)v[0]; h[1] = (bf16)v[1]; h[2] = (bf16)v[2]; h[3] = (bf16)v[3];
            *(bf16x4*)(xb + (size_t)(t0 + row) * DI + k + cf4 * 4) = h;
            int byte = row * 128 + ((cf4 * 8) ^ ((row & 7) << 4));
            *(bf16x4*)((char*)sA + byte) = h;
        }
#pragma unroll
        for (int j = 0; j < 4; ++j) {
            int ci = j * 256 + tid;
            int row = ci >> 3;
            int sl = (ci & 7) ^ (row & 7);
            gload_lds16(wab + (size_t)row * DI + k + sl * 8, sB + ci * 8);
        }
        __syncthreads();
#pragma unroll
        for (int ks = 0; ks < 2; ++ks) {
            bf16x8 af[4], bg[4];
#pragma unroll
            for (int mi = 0; mi < 4; ++mi) {
                int row = wr * 64 + mi * 16 + (lane & 15);
                int byte = row * 128 + (((ks * 64) + (lane >> 4) * 16) ^ ((row & 7) << 4));
                af[mi] = *(const bf16x8*)((const char*)sA + byte);
            }
#pragma unroll
            for (int ni = 0; ni < 4; ++ni) {
                int row = wc * 64 + ni * 16 + (lane & 15);
                int byte = row * 128 + (((ks * 64) + (lane >> 4) * 16) ^ ((row & 7) << 4));
                bg[ni] = *(const bf16x8*)((const char*)sB + byte);
            }
#pragma unroll
            for (int mi = 0; mi < 4; ++mi)
#pragma unroll
                for (int ni = 0; ni < 4; ++ni)
                    acc[mi][ni] = __builtin_amdgcn_mfma_f32_16x16x32_bf16(
                        af[mi], bg[ni], acc[mi][ni], 0, 0, 0);
        }
        __syncthreads();
    }

    const int qw = lane >> 4, cl = lane & 15;
#pragma unroll
    for (int mi = 0; mi < 4; ++mi) {
#pragma unroll
        for (int rr = 0; rr < 4; ++rr) {
            int t = t0 + wr * 64 + mi * 16 + qw * 4 + rr;
            int lt = tl[t];
            float s = scaling[lt];
#pragma unroll
            for (int ni = 0; ni < 4; ++ni) {
                int lr = wc * 64 + ni * 16 + cl;
                if ((lr >> 4) == lt)
                    atomicAdd(&u[t * RLORA + (lr & 15)], s * acc[mi][ni][rr]);
            }
        }
    }
}

// ---------------- Main: 256x256 8-phase bf16 GEMM + fused epilogue ----------
// 512 thr = 8 waves (2M x 4N); wave tile 128x64; BK=64; LDS 128 KiB
// (A[2][256][64] + B[2][256][64] bf16). Counted vmcnt, raw s_barrier.
__global__ __launch_bounds__(512, 2) void gemm_main(
    const bf16* __restrict__ xb, const bf16* __restrict__ wkb,
    const float* __restrict__ bb, const float* __restrict__ WBw,
    const float* __restrict__ u, const int* __restrict__ tl,
    float* __restrict__ out)
{
    __shared__ bf16 smem[65536]; // bytes: sA [0,65536) = 2 bufs x 32KiB; sB [65536,131072)
    const int tid  = threadIdx.x;
    const int lane = tid & 63;
    const int wv   = tid >> 6;
    const int wr = wv >> 2, wc = wv & 3;         // 2 x 4 waves
    const int l15 = lane & 15, hi4 = lane >> 4, l7 = lane & 7;

    // XCD swizzle (512 % 8 == 0): chunk of 64 = 2 bn x 32 bm (shares B panels in L2)
    int s = (blockIdx.x & 7) * 64 + (blockIdx.x >> 3);
    const int bn = s >> 5, bm = s & 31;
    const int brow = bm * 256, bcol = bn * 256;

    const bf16* gA = xb  + (size_t)brow * DI;
    const bf16* gB = wkb + (size_t)bcol * DI;

    f32x4 acc[8][4] = {};
    bf16x8 afr[4][2], bfr[4][2];

    // stage one half-tile (128 rows x 64 cols bf16 = 16 KiB): 2 gload_lds/thread.
    // LDS linear; swizzle applied on GLOBAL source column slot (involution).
    auto STAGE = [&](int buf, int isA, int half, int kt) {
        const bf16* g = isA ? gA : gB;
        bf16* l = smem + (isA ? 0 : 32768) + buf * 16384 + half * 8192;
#pragma unroll
        for (int j = 0; j < 2; ++j) {
            int chunk = j * 512 + tid;
            int r = chunk >> 3, sl = chunk & 7;
            gload_lds16(g + (size_t)(half * 128 + r) * DI + kt * 64 + ((sl ^ (r & 7)) * 8),
                        l + chunk * 8);
        }
    };
    auto READ_A = [&](int buf, int mh) {
        const char* base = (const char*)smem + buf * 32768 + (wr * 128 + l15) * 128;
#pragma unroll
        for (int mi = 0; mi < 4; ++mi)
#pragma unroll
            for (int kk = 0; kk < 2; ++kk)
                afr[mi][kk] = *(const bf16x8*)(base + (mh * 4 + mi) * 2048 +
                                  (((kk * 4 + hi4) ^ l7) * 16));
    };
    auto READ_B = [&](int buf, int nh) {
        const char* base = (const char*)smem + 65536 + buf * 32768 + (wc * 64 + l15) * 128;
#pragma unroll
        for (int ni = 0; ni < 2; ++ni)
#pragma unroll
            for (int kk = 0; kk < 2; ++kk)
                bfr[nh * 2 + ni][kk] = *(const bf16x8*)(base + (nh * 2 + ni) * 2048 +
                                  (((kk * 4 + hi4) ^ l7) * 16));
    };
    auto MFMA_Q = [&](int mh, int nh) {
        __builtin_amdgcn_s_setprio(1);
#pragma unroll
        for (int kk = 0; kk < 2; ++kk)
#pragma unroll
            for (int mi = 0; mi < 4; ++mi)
#pragma unroll
                for (int ni = 0; ni < 2; ++ni)
                    acc[mh * 4 + mi][nh * 2 + ni] = __builtin_amdgcn_mfma_f32_16x16x32_bf16(
                        afr[mi][kk], bfr[nh * 2 + ni][kk], acc[mh * 4 + mi][nh * 2 + ni], 0, 0, 0);
        __builtin_amdgcn_s_setprio(0);
    };

    // one K-tile = 4 phases. A-halves of t+1 staged P1/P2 (opposite buf, free since
    // last read at P3 of t-1); B-halves of t+2 staged P3/P4 (same buf, free after P2).
    auto TILE = [&](int D, int T) {
        // P1: quadrant (m0,n0)
        READ_A(D, 0); READ_B(D, 0);
        if (T + 1 < NKT) STAGE(D ^ 1, 1, 0, T + 1);
        __builtin_amdgcn_s_barrier();
        MFMA_Q(0, 0);
        __builtin_amdgcn_s_barrier();
        // P2: (m0,n1)
        READ_B(D, 1);
        if (T + 1 < NKT) STAGE(D ^ 1, 1, 1, T + 1);
        __builtin_amdgcn_s_barrier();
        MFMA_Q(0, 1);
        __builtin_amdgcn_s_barrier();
        // P3: (m1,n1)
        READ_A(D, 1);
        if (T + 2 < NKT) STAGE(D, 0, 0, T + 2);
        __builtin_amdgcn_s_barrier();
        MFMA_Q(1, 1);
        __builtin_amdgcn_s_barrier();
        // P4: (m1,n0) — counted vmcnt: leaves B0,B1(T+2) = 4 loads in flight
        if (T + 2 < NKT) STAGE(D, 0, 1, T + 2);
        if (T < NKT - 2) { asm volatile("s_waitcnt vmcnt(4)" ::: "memory"); }
        else             { asm volatile("s_waitcnt vmcnt(0)" ::: "memory"); }
        __builtin_amdgcn_s_barrier();
        MFMA_Q(1, 0);
        __builtin_amdgcn_s_barrier();
    };

    // prologue: tile0 (B0,B1,A0,A1) + tile1 (B0,B1); wait leaves tile1 B-halves in flight
    STAGE(0, 0, 0, 0); STAGE(0, 0, 1, 0); STAGE(0, 1, 0, 0); STAGE(0, 1, 1, 0);
    STAGE(1, 0, 0, 1); STAGE(1, 0, 1, 1);
    asm volatile("s_waitcnt vmcnt(4)" ::: "memory");
    __builtin_amdgcn_s_barrier();

#pragma unroll 1
    for (int tt = 0; tt < NKT; tt += 2) {
        TILE(0, tt);
        TILE(1, tt + 1);
    }

    // ---- epilogue: out = acc + b + dot16(u_scaled[t], WB[l_t][o]) ----
    float* uld = (float*)smem;                 // [256][16] f32 = 16 KiB
    int*   tld = (int*)((char*)smem + 16384);  // 256 ints
    {
        const f32x4* ug = (const f32x4*)(u + (size_t)brow * RLORA);
        f32x4* us = (f32x4*)uld;
        us[tid]       = ug[tid];
        us[512 + tid] = ug[512 + tid];
        if (tid < 256) tld[tid] = tl[brow + tid];
    }
    __syncthreads();
    const int luni = (tld[0] == tld[255]) ? tld[0] : -1; // sorted tokens

    int   ocol[4];
    float bv[4];
#pragma unroll
    for (int ni = 0; ni < 4; ++ni) {
        ocol[ni] = bcol + wc * 64 + ni * 16 + l15;
        bv[ni] = bb[ocol[ni]];
    }
    f32x4 wbv[4][4];
    if (luni >= 0) {
#pragma unroll
        for (int ni = 0; ni < 4; ++ni) {
            const f32x4* wp = (const f32x4*)(WBw + ((size_t)luni * DOUT + ocol[ni]) * RLORA);
#pragma unroll
            for (int j = 0; j < 4; ++j) wbv[ni][j] = wp[j];
        }
    }

#pragma unroll
    for (int mi = 0; mi < 8; ++mi) {
#pragma unroll
        for (int rr = 0; rr < 4; ++rr) {
            int t_loc = wr * 128 + mi * 16 + hi4 * 4 + rr;
            const float* uv = uld + t_loc * 16;
            int lt = (luni >= 0) ? luni : tld[t_loc];
            float* op = out + (size_t)(brow + t_loc) * DOUT;
#pragma unroll
            for (int ni = 0; ni < 4; ++ni) {
                f32x4 w0, w1, w2, w3;
                if (luni >= 0) {
                    w0 = wbv[ni][0]; w1 = wbv[ni][1]; w2 = wbv[ni][2]; w3 = wbv[ni][3];
                } else {
                    const f32x4* wp = (const f32x4*)(WBw + ((size_t)lt * DOUT + ocol[ni]) * RLORA);
                    w0 = wp[0]; w1 = wp[1]; w2 = wp[2]; w3 = wp[3];
                }
                float dot = 0.f;
#pragma unroll
                for (int r = 0; r < 4; ++r)
                    dot += uv[r] * w0[r] + uv[4 + r] * w1[r]
                         + uv[8 + r] * w2[r] + uv[12 + r] * w3[r];
                op[ocol[ni]] = acc[mi][ni][rr] + bv[ni] + dot;
            }
        }
    }
}

extern "C" void kernel_launch(void* const* d_in, const int* in_sizes, int n_in,
                              void* d_out, int out_size, void* d_ws, size_t ws_size,
                              hipStream_t stream) {
    const float* x   = (const float*)d_in[0];
    const float* W   = (const float*)d_in[1];
    const float* bb  = (const float*)d_in[2];
    const float* WA  = (const float*)d_in[3];
    const float* WBw = (const float*)d_in[4];
    const float* sc  = (const float*)d_in[5];
    const int*   tl  = (const int*)d_in[6];
    float* out = (float*)d_out;

    char* ws = (char*)d_ws;
    bf16*  xb  = (bf16*)(ws + XB_OFF);
    bf16*  wkb = (bf16*)(ws + WKB_OFF);
    bf16*  wab = (bf16*)(ws + WAB_OFF);
    float* u   = (float*)(ws + U_OFF);

    hipMemsetAsync(u, 0, (size_t)TT * RLORA * sizeof(float), stream);
    convert_w<<<2048, 256, 0, stream>>>(W, WA, wkb, wab);
    prep_x_u<<<512, 256, 0, stream>>>(x, wab, sc, tl, xb, u);
    gemm_main<<<512, 512, 0, stream>>>(xb, wkb, bb, WBw, u, tl, out);
}